// Round 9
// baseline (309.435 us; speedup 1.0000x reference)
//
#include <hip/hip_runtime.h>

// SoftTriple loss, MI355X. B=256, E=512, C=8192, K=10.
// Round 9: prep rebuilt barrier-free. r8 measured prep at 103.8us vs a
// 40us traffic floor (VALUBusy 43%, hbm 1.6TB/s): block-per-class with 2
// barriers + LDS round-trip exposes HBM latency 32x per CU. Now: wave w
// owns class blockIdx*4+w; lane holds ra[10][2] float4 (its 8 elems of
// each row); 20 loads issued back-to-back, NO barriers, NO LDS; norms +
// 45 gram pairs via butterfly shfl (identical fp32 math, verified r3);
// normalized bf16 rows stored directly to w (1KB contiguous per row).
// gemm (BK=64 dbuf, swizzled staging) + fused-CE epilogue + final: r8 code.
// ws layout (bytes):
//   [0, 83886080)        w  bf16 [81920][512]  (normalized, compact)
//   [83886080, 84148224) At bf16 [16][256][32] (k-chunked emb)
//   [84148224, 84180992) gram_part float[8192]
//   [84181248, 84182272) sumexp  float[256]
//   [84182272, 84183296) lab_logit float[256]

typedef __bf16 bf16;
typedef bf16 bf16x8 __attribute__((ext_vector_type(8)));
typedef float f32x4 __attribute__((ext_vector_type(4)));

#define NCLASS 8192
#define KC 10
#define EDIM 512
#define BATCH 256
#define BK 64

__device__ inline void load_lds16(const void* g, void* l) {
    __builtin_amdgcn_global_load_lds(
        (const __attribute__((address_space(1))) void*)g,
        (__attribute__((address_space(3))) void*)l, 16, 0, 0);
}

// ---------------- kernel 1: normalize + gram (reg-resident) + conv --------
// blocks [0,2048): prep, 4 classes/block (1 wave = 1 class), barrier-free.
// blocks [2048,2112): emb->At conv. block 2112: zero sumexp.
__global__ __launch_bounds__(256) void prep_kernel(
    const float* __restrict__ fc, bf16* __restrict__ w,
    float* __restrict__ gram_part,
    const float* __restrict__ e, bf16* __restrict__ At,
    float* __restrict__ sumexp)
{
    const int t = threadIdx.x;

    if (blockIdx.x >= 2048) {
        if (blockIdx.x == 2048 + 64) {        // zero the CE accumulator
            sumexp[t] = 0.0f;
            return;
        }
        // ---- emb fp32 -> bf16, k-chunk transposed: At[k>>5][row][k&31] ----
        int i = (blockIdx.x - 2048) * 256 + t;
        int row = i >> 6, chunk = i & 63;
        int k = chunk * 8;
        float4 a = ((const float4*)e)[i * 2];
        float4 b = ((const float4*)e)[i * 2 + 1];
        bf16x8 v;
        v[0] = (bf16)a.x; v[1] = (bf16)a.y; v[2] = (bf16)a.z; v[3] = (bf16)a.w;
        v[4] = (bf16)b.x; v[5] = (bf16)b.y; v[6] = (bf16)b.z; v[7] = (bf16)b.w;
        *(bf16x8*)&At[((k >> 5) << 13) + (row << 5) + (k & 31)] = v;
        return;
    }

    const int wave = t >> 6, lane = t & 63;
    const int c = blockIdx.x * 4 + wave;

    // load class: lane holds elems [lane*8, lane*8+8) of each of 10 rows.
    // 20 back-to-back global loads, no barrier.
    float4 ra[KC][2];
    #pragma unroll
    for (int r = 0; r < KC; ++r) {
        const float4* rp =
            (const float4*)(fc + ((size_t)c * KC + r) * EDIM) + lane * 2;
        ra[r][0] = rp[0];
        ra[r][1] = rp[1];
    }

    // row inv-norms via butterfly reduce
    float invn[KC];
    #pragma unroll
    for (int r = 0; r < KC; ++r) {
        float4 a = ra[r][0], b = ra[r][1];
        float s = a.x*a.x + a.y*a.y + a.z*a.z + a.w*a.w
                + b.x*b.x + b.y*b.y + b.z*b.z + b.w*b.w;
        #pragma unroll
        for (int off = 32; off; off >>= 1) s += __shfl_xor(s, off);
        invn[r] = 1.0f / fmaxf(sqrtf(s), 1e-12f);
    }

    // gram regularizer: 45 strict-upper pairs, fp32 (verified r3 math)
    float part = 0.f;
    #pragma unroll
    for (int i = 0; i < KC - 1; ++i) {
        #pragma unroll
        for (int j = i + 1; j < KC; ++j) {
            float4 ai = ra[i][0], bi = ra[i][1];
            float4 aj = ra[j][0], bj = ra[j][1];
            float s = ai.x*aj.x + ai.y*aj.y + ai.z*aj.z + ai.w*aj.w
                    + bi.x*bj.x + bi.y*bj.y + bi.z*bj.z + bi.w*bj.w;
            #pragma unroll
            for (int off = 32; off; off >>= 1) s += __shfl_xor(s, off);
            float sub = 1.0f - s * invn[i] * invn[j];
            if (sub <= 0.0f) sub = 1e-10f;
            part += sqrtf(2.0f * sub);
        }
    }
    if (lane == 0) gram_part[c] = part;

    // normalized bf16 write: 16B/lane, 1KB contiguous per row
    #pragma unroll
    for (int r = 0; r < KC; ++r) {
        float inv = invn[r];
        float4 a = ra[r][0], b = ra[r][1];
        bf16x8 v;
        v[0] = (bf16)(a.x * inv); v[1] = (bf16)(a.y * inv);
        v[2] = (bf16)(a.z * inv); v[3] = (bf16)(a.w * inv);
        v[4] = (bf16)(b.x * inv); v[5] = (bf16)(b.y * inv);
        v[6] = (bf16)(b.z * inv); v[7] = (bf16)(b.w * inv);
        *(bf16x8*)&w[((size_t)c * KC + r) * EDIM + lane * 8] = v;
    }
}

// ---------------- kernel 2: GEMM + softmax-K + fused CE partials ----------
// PACKED M: BM=80 rows = 8 classes/block. 512 threads = 8 waves, wave grid
// 1m x 8n: each wave = 80 rows x 32 batch cols (5mt x 2nt MFMA 16x16x32).
// BK=64 double-buffered (verified r7). Epilogue: per-class softmax over
// K=10 (verified r2) + fused CE partials (verified r8).
__global__ __launch_bounds__(512, 2) void gemm_h_kernel(
    const bf16* __restrict__ W,    // [81920][512] compact normalized centers
    const bf16* __restrict__ At,   // [16][256][32] emb bf16
    const int* __restrict__ labels,
    float* __restrict__ sumexp,    // [256] CE partial sums
    float* __restrict__ lab_logit) // [256]
{
    __shared__ bf16 Ws[2][80 * BK];   // 2 x 10 KB
    const int tid = threadIdx.x;
    const int wave = tid >> 6, lane = tid & 63;

    f32x4 acc[5][2];
    #pragma unroll
    for (int mt = 0; mt < 5; ++mt)
        #pragma unroll
        for (int nt = 0; nt < 2; ++nt)
            acc[mt][nt] = (f32x4){0.f, 0.f, 0.f, 0.f};

    const size_t g0 = (size_t)blockIdx.x * 80;   // first packed W row

    // staging: slot j in [0,640): row=j>>3, s=j&7, global chunk = s^(row&7).
    const int rA = tid >> 3, sA = tid & 7;
    const bf16* srcA = W + (g0 + rA) * EDIM + ((sA ^ (rA & 7)) << 3);
    const int rB = (512 + tid) >> 3, sB = tid & 7;
    const bf16* srcB = W + (g0 + rB) * EDIM + ((sB ^ (rB & 7)) << 3);

    const int q = lane >> 4;        // fragment chunk within 32-k
    const int q8 = q * 8;
    const int fr = lane & 15;

    // prologue: stage tile 0 into buf 0
    load_lds16(srcA, &Ws[0][wave * 512]);
    if (tid < 128) load_lds16(srcB, &Ws[0][4096 + wave * 512]);
    __syncthreads();

    for (int t = 0; t < 8; ++t) {
        const int cur = t & 1;
        if (t < 7) {
            const int kb = (t + 1) * BK;
            load_lds16(srcA + kb, &Ws[cur ^ 1][wave * 512]);
            if (tid < 128) load_lds16(srcB + kb, &Ws[cur ^ 1][4096 + wave * 512]);
        }
        #pragma unroll
        for (int kk = 0; kk < BK; kk += 32) {
            const int ccb = kk >> 3;             // 0 or 4
            bf16x8 wf[5], ef[2];
            #pragma unroll
            for (int nt = 0; nt < 2; ++nt) {
                int row = wave * 32 + nt * 16 + fr;
                ef[nt] = *(const bf16x8*)
                    &At[((t * 2 + (kk >> 5)) << 13) + (row << 5) + q8];
            }
            #pragma unroll
            for (int mt = 0; mt < 5; ++mt) {
                int row = mt * 16 + fr;
                int s = (ccb + q) ^ (row & 7);
                wf[mt] = *(const bf16x8*)&Ws[cur][row * BK + (s << 3)];
            }
            #pragma unroll
            for (int mt = 0; mt < 5; ++mt)
                #pragma unroll
                for (int nt = 0; nt < 2; ++nt)
                    acc[mt][nt] = __builtin_amdgcn_mfma_f32_16x16x32_bf16(
                        wf[mt], ef[nt], acc[mt][nt], 0, 0, 0);
        }
        __syncthreads();
    }

    // epilogue: packed row r = 16*mt + 4*quad + reg; class c = r/10.
    const int col = lane & 15;
    const int quad = lane >> 4;
    const int cb = blockIdx.x * 8;
    #pragma unroll
    for (int nt = 0; nt < 2; ++nt) {
        int b = wave * 32 + nt * 16 + col;
        float hval[8];
        #pragma unroll
        for (int cc = 0; cc < 8; ++cc) {
            float xm = -1e30f;
            #pragma unroll
            for (int mt = 0; mt < 5; ++mt) {
                if (10 * cc + 10 > 16 * mt && 10 * cc < 16 * mt + 16) { // static
                    #pragma unroll
                    for (int rg = 0; rg < 4; ++rg) {
                        int r = 16 * mt + 4 * quad + rg;
                        if (r >= 10 * cc && r < 10 * cc + 10)          // runtime
                            xm = fmaxf(xm, acc[mt][nt][rg]);
                    }
                }
            }
            xm = fmaxf(xm, __shfl_xor(xm, 16));
            xm = fmaxf(xm, __shfl_xor(xm, 32));
            float s1 = 0.f, s2 = 0.f;
            #pragma unroll
            for (int mt = 0; mt < 5; ++mt) {
                if (10 * cc + 10 > 16 * mt && 10 * cc < 16 * mt + 16) { // static
                    #pragma unroll
                    for (int rg = 0; rg < 4; ++rg) {
                        int r = 16 * mt + 4 * quad + rg;
                        if (r >= 10 * cc && r < 10 * cc + 10) {        // runtime
                            float x = acc[mt][nt][rg];
                            float e = __expf(10.0f * (x - xm));
                            s1 += e; s2 += e * x;
                        }
                    }
                }
            }
            s1 += __shfl_xor(s1, 16); s1 += __shfl_xor(s1, 32);
            s2 += __shfl_xor(s2, 16); s2 += __shfl_xor(s2, 32);
            hval[cc] = s2 / s1;
        }
        if (quad == 0) {
            // fused CE partial: logits bounded (|10h| < ~50) -> no shift
            const int lbl = labels[b];
            float ps = 0.f;
            #pragma unroll
            for (int cc = 0; cc < 8; ++cc) {
                float lg = 10.0f * hval[cc];
                if (lbl == cb + cc) {
                    lg -= 0.1f;               // LMD * MARGIN
                    lab_logit[b] = lg;        // single writer per b
                }
                ps += __expf(lg);
            }
            atomicAdd(&sumexp[b], ps);
        }
    }
}

// ---------------- kernel 3: reduce partials + combine ---------------------
__global__ __launch_bounds__(256) void final_kernel(
    const float* __restrict__ gram_part, const float* __restrict__ sumexp,
    const float* __restrict__ lab_logit, float* __restrict__ out)
{
    __shared__ float red[4];
    const int t = threadIdx.x, wave = t >> 6, lane = t & 63;
    const float4* gp4 = (const float4*)gram_part;
    float g = 0.f;
    #pragma unroll
    for (int i = 0; i < 8; ++i) {
        float4 x = gp4[t + i * 256];
        g += x.x + x.y + x.z + x.w;
    }
    float ce = logf(sumexp[t]) - lab_logit[t];   // -logp[label], no shift
    float val = ce * (1.0f / 256.0f)
              + g * (0.2f / 737280.0f);          // C*K*(K-1) = 737280
    #pragma unroll
    for (int off = 32; off; off >>= 1) val += __shfl_xor(val, off);
    if (lane == 0) red[wave] = val;
    __syncthreads();
    if (t == 0) out[0] = red[0] + red[1] + red[2] + red[3];
}

extern "C" void kernel_launch(void* const* d_in, const int* in_sizes, int n_in,
                              void* d_out, int out_size, void* d_ws, size_t ws_size,
                              hipStream_t stream) {
    const float* emb    = (const float*)d_in[0];   // [256][512]
    const int*   labels = (const int*)d_in[1];     // [256]
    const float* fc     = (const float*)d_in[2];   // [81920][512]
    float* out = (float*)d_out;

    char* ws = (char*)d_ws;
    bf16*  w         = (bf16*)ws;                        //  83886080 B
    bf16*  At        = (bf16*)(ws + 83886080);           //    262144 B
    float* gram_part = (float*)(ws + 84148224);          //     32768 B
    float* sumexp    = (float*)(ws + 84181248);          //      1024 B
    float* lab_logit = (float*)(ws + 84182272);          //      1024 B

    prep_kernel<<<2048 + 65, 256, 0, stream>>>(fc, w, gram_part, emb, At,
                                               sumexp);
    gemm_h_kernel<<<81920 / 80, 512, 0, stream>>>(w, At, labels,
                                                  sumexp, lab_logit);
    final_kernel<<<1, 256, 0, stream>>>(gram_part, sumexp, lab_logit, out);
}

// Round 10
// 267.048 us; speedup vs baseline: 1.1587x; 1.1587x over previous
//
#include <hip/hip_runtime.h>

// SoftTriple loss, MI355X. B=256, E=512, C=8192, K=10.
// Round 10: prep_kernel ELIMINATED. Normalization commutes with the GEMM
// (w_r.e = invn_r*(fc_r.e)), so the GEMM runs on RAW fc (bf16-converted
// during reg-staging, fc read ONCE = 168MB) and scales acc by invn in the
// epilogue. invn + gram come from ONE extra MFMA per wave per kk:
// gacc = mfma(wf_g, wf_g) on the class-aligned 16-row fragment gives all
// within-class dot products; diag = row norms, upper-tri (rr<col<10) = the
// 45 gram pairs. w round-trip (84+84 MB) and the whole prep kernel vanish.
// GEMM core (BK=64 dbuf, slot s holds chunk s^(row&7)) + softmax-K +
// fused-CE epilogue: verified r7/r8 code.
// ws layout (bytes):
//   [0, 262144)        At bf16 [16][256][32] (k-chunked emb)
//   [262144, 263168)   sumexp  float[256]
//   [263168, 264192)   lab_logit float[256]
//   [264192, 264196)   gram_sum float[1]

typedef __bf16 bf16;
typedef bf16 bf16x8 __attribute__((ext_vector_type(8)));
typedef float f32x4 __attribute__((ext_vector_type(4)));

#define NCLASS 8192
#define KC 10
#define EDIM 512
#define BATCH 256
#define BK 64

// ---------------- kernel 1: emb conv + accumulator zeroing ----------------
// blocks [0,64): emb fp32 -> bf16 k-chunk transposed At. block 64: zero.
__global__ __launch_bounds__(256) void conv_kernel(
    const float* __restrict__ e, bf16* __restrict__ At,
    float* __restrict__ sumexp, float* __restrict__ gram_sum)
{
    const int t = threadIdx.x;
    if (blockIdx.x == 64) {
        sumexp[t] = 0.0f;
        if (t == 0) gram_sum[0] = 0.0f;
        return;
    }
    int i = blockIdx.x * 256 + t;
    int row = i >> 6, chunk = i & 63;
    int k = chunk * 8;
    float4 a = ((const float4*)e)[i * 2];
    float4 b = ((const float4*)e)[i * 2 + 1];
    bf16x8 v;
    v[0] = (bf16)a.x; v[1] = (bf16)a.y; v[2] = (bf16)a.z; v[3] = (bf16)a.w;
    v[4] = (bf16)b.x; v[5] = (bf16)b.y; v[6] = (bf16)b.z; v[7] = (bf16)b.w;
    *(bf16x8*)&At[((k >> 5) << 13) + (row << 5) + (k & 31)] = v;
}

// ---------------- kernel 2: everything-GEMM --------------------------------
// 1024 blocks x 512 thr (8 waves). Per block: 8 classes = 80 packed raw-fc
// rows. K-loop: reg-stage fc fp32->bf16 into dbuf Ws (slot s of row holds
// global chunk s^(row&7)), 5mt x 2nt main MFMA + 1 gram MFMA per wave/kk.
// Epilogue: diag(gacc)->ssq->invn (LDS); gram pairs -> block atomicAdd;
// acc *= invn[row]; per-class softmax-K + fused CE (r8-verified).
__global__ __launch_bounds__(512, 2) void gemm_all_kernel(
    const float* __restrict__ fc,  // [81920][512] raw centers fp32
    const bf16* __restrict__ At,   // [16][256][32] emb bf16
    const int* __restrict__ labels,
    float* __restrict__ sumexp,    // [256]
    float* __restrict__ lab_logit, // [256]
    float* __restrict__ gram_sum)  // [1]
{
    __shared__ bf16 Ws[2][80 * BK];   // 2 x 10 KB
    const int tid = threadIdx.x;
    const int wave = tid >> 6, lane = tid & 63;

    f32x4 acc[5][2];
    #pragma unroll
    for (int mt = 0; mt < 5; ++mt)
        #pragma unroll
        for (int nt = 0; nt < 2; ++nt)
            acc[mt][nt] = (f32x4){0.f, 0.f, 0.f, 0.f};
    f32x4 gacc = (f32x4){0.f, 0.f, 0.f, 0.f};

    const size_t g0 = (size_t)blockIdx.x * 80;   // first packed fc row

    // staging geometry: slot j in [0,640): row=j>>3, s=j&7 holds global
    // chunk gc = s^(row&7) (8 floats = 32B). slotA = tid; slotB = 512+tid
    // (waves 0-1 only -> wave-uniform branch).
    const int rowA = tid >> 3, sA = tid & 7;
    const float* srcA = fc + (g0 + rowA) * EDIM + ((sA ^ (rowA & 7)) << 3);
    const int rowB = (512 + tid) >> 3, sB = tid & 7;
    const float* srcB = fc + (g0 + rowB) * EDIM + ((sB ^ (rowB & 7)) << 3);
    const bool hasB = (tid < 128);
    const int ldsA = rowA * BK + sA * 8;
    const int ldsB = rowB * BK + sB * 8;

    const int q = lane >> 4;        // fragment chunk within 32-k
    const int q8 = q * 8;
    const int fr = lane & 15;
    const int grow = min(10 * wave + fr, 79);   // class-aligned gram row

    // prologue: stage tile 0 into buf 0
    {
        float4 a0 = ((const float4*)srcA)[0];
        float4 a1 = ((const float4*)srcA)[1];
        bf16x8 va;
        va[0]=(bf16)a0.x; va[1]=(bf16)a0.y; va[2]=(bf16)a0.z; va[3]=(bf16)a0.w;
        va[4]=(bf16)a1.x; va[5]=(bf16)a1.y; va[6]=(bf16)a1.z; va[7]=(bf16)a1.w;
        *(bf16x8*)&Ws[0][ldsA] = va;
        if (hasB) {
            float4 b0 = ((const float4*)srcB)[0];
            float4 b1 = ((const float4*)srcB)[1];
            bf16x8 vb;
            vb[0]=(bf16)b0.x; vb[1]=(bf16)b0.y; vb[2]=(bf16)b0.z; vb[3]=(bf16)b0.w;
            vb[4]=(bf16)b1.x; vb[5]=(bf16)b1.y; vb[6]=(bf16)b1.z; vb[7]=(bf16)b1.w;
            *(bf16x8*)&Ws[0][ldsB] = vb;
        }
    }
    __syncthreads();

    for (int t = 0; t < 8; ++t) {
        const int cur = t & 1;
        // issue next-tile loads FIRST (latency hides under the MFMAs below)
        float4 a0, a1, b0, b1;
        if (t < 7) {
            const int k0 = (t + 1) * BK;
            a0 = ((const float4*)(srcA + k0))[0];
            a1 = ((const float4*)(srcA + k0))[1];
            if (hasB) {
                b0 = ((const float4*)(srcB + k0))[0];
                b1 = ((const float4*)(srcB + k0))[1];
            }
        }
        // compute current tile
        #pragma unroll
        for (int kk = 0; kk < BK; kk += 32) {
            const int ccb = kk >> 3;             // 0 or 4
            bf16x8 wf[5], ef[2], wg;
            #pragma unroll
            for (int nt = 0; nt < 2; ++nt) {
                int row = wave * 32 + nt * 16 + fr;
                ef[nt] = *(const bf16x8*)
                    &At[((t * 2 + (kk >> 5)) << 13) + (row << 5) + q8];
            }
            #pragma unroll
            for (int mt = 0; mt < 5; ++mt) {
                int row = mt * 16 + fr;
                int s = (ccb + q) ^ (row & 7);
                wf[mt] = *(const bf16x8*)&Ws[cur][row * BK + (s << 3)];
            }
            {
                int s = (ccb + q) ^ (grow & 7);
                wg = *(const bf16x8*)&Ws[cur][grow * BK + (s << 3)];
            }
            #pragma unroll
            for (int mt = 0; mt < 5; ++mt)
                #pragma unroll
                for (int nt = 0; nt < 2; ++nt)
                    acc[mt][nt] = __builtin_amdgcn_mfma_f32_16x16x32_bf16(
                        wf[mt], ef[nt], acc[mt][nt], 0, 0, 0);
            gacc = __builtin_amdgcn_mfma_f32_16x16x32_bf16(wg, wg, gacc, 0, 0, 0);
        }
        // write next tile into the other buffer
        if (t < 7) {
            bf16x8 va;
            va[0]=(bf16)a0.x; va[1]=(bf16)a0.y; va[2]=(bf16)a0.z; va[3]=(bf16)a0.w;
            va[4]=(bf16)a1.x; va[5]=(bf16)a1.y; va[6]=(bf16)a1.z; va[7]=(bf16)a1.w;
            *(bf16x8*)&Ws[cur ^ 1][ldsA] = va;
            if (hasB) {
                bf16x8 vb;
                vb[0]=(bf16)b0.x; vb[1]=(bf16)b0.y; vb[2]=(bf16)b0.z; vb[3]=(bf16)b0.w;
                vb[4]=(bf16)b1.x; vb[5]=(bf16)b1.y; vb[6]=(bf16)b1.z; vb[7]=(bf16)b1.w;
                *(bf16x8*)&Ws[cur ^ 1][ldsB] = vb;
            }
        }
        __syncthreads();
    }

    // ---- gram/norm epilogue. gacc: D[4*quad+rg][lane&15] = dot(raw rows
    // 10*wave+rr, 10*wave+col). Diag -> ssq -> invn (LDS, reusing Ws). ----
    float* fbuf = (float*)&Ws[0][0];
    const int col = lane & 15;
    const int quad = lane >> 4;
    #pragma unroll
    for (int rg = 0; rg < 4; ++rg) {
        if ((col >> 2) == quad && (col & 3) == rg) {
            int pr = 10 * wave + col;
            if (pr < 80) fbuf[pr] = gacc[rg];   // overlapping waves: same value
        }
    }
    __syncthreads();
    if (tid < 80) fbuf[80 + tid] = 1.0f / fmaxf(sqrtf(fbuf[tid]), 1e-12f);
    __syncthreads();
    const float* invn = fbuf + 80;

    // gram pairs: rr < col < 10 within class `wave`
    float part = 0.f;
    #pragma unroll
    for (int rg = 0; rg < 4; ++rg) {
        int rr = 4 * quad + rg;
        if (rr < col && col < 10) {
            float s_cos = gacc[rg] * invn[10 * wave + rr] * invn[10 * wave + col];
            float sub = 1.0f - s_cos;
            if (sub <= 0.0f) sub = 1e-10f;
            part += sqrtf(2.0f * sub);
        }
    }
    #pragma unroll
    for (int off = 32; off; off >>= 1) part += __shfl_xor(part, off);
    if (lane == 0) fbuf[160 + wave] = part;
    __syncthreads();
    if (tid == 0) {
        float g = 0.f;
        #pragma unroll
        for (int wv = 0; wv < 8; ++wv) g += fbuf[160 + wv];
        atomicAdd(gram_sum, g);
    }

    // ---- scale acc by invn (normalization commutes with the GEMM) ----
    #pragma unroll
    for (int mt = 0; mt < 5; ++mt)
        #pragma unroll
        for (int rg = 0; rg < 4; ++rg) {
            float iv = invn[16 * mt + 4 * quad + rg];
            acc[mt][0][rg] *= iv;
            acc[mt][1][rg] *= iv;
        }

    // ---- main epilogue: packed row r = 16*mt+4*quad+rg; class = r/10 ----
    const int cb = blockIdx.x * 8;
    #pragma unroll
    for (int nt = 0; nt < 2; ++nt) {
        int b = wave * 32 + nt * 16 + col;
        float hval[8];
        #pragma unroll
        for (int cc = 0; cc < 8; ++cc) {
            float xm = -1e30f;
            #pragma unroll
            for (int mt = 0; mt < 5; ++mt) {
                if (10 * cc + 10 > 16 * mt && 10 * cc < 16 * mt + 16) { // static
                    #pragma unroll
                    for (int rg = 0; rg < 4; ++rg) {
                        int r = 16 * mt + 4 * quad + rg;
                        if (r >= 10 * cc && r < 10 * cc + 10)          // runtime
                            xm = fmaxf(xm, acc[mt][nt][rg]);
                    }
                }
            }
            xm = fmaxf(xm, __shfl_xor(xm, 16));
            xm = fmaxf(xm, __shfl_xor(xm, 32));
            float s1 = 0.f, s2 = 0.f;
            #pragma unroll
            for (int mt = 0; mt < 5; ++mt) {
                if (10 * cc + 10 > 16 * mt && 10 * cc < 16 * mt + 16) { // static
                    #pragma unroll
                    for (int rg = 0; rg < 4; ++rg) {
                        int r = 16 * mt + 4 * quad + rg;
                        if (r >= 10 * cc && r < 10 * cc + 10) {        // runtime
                            float x = acc[mt][nt][rg];
                            float e = __expf(10.0f * (x - xm));
                            s1 += e; s2 += e * x;
                        }
                    }
                }
            }
            s1 += __shfl_xor(s1, 16); s1 += __shfl_xor(s1, 32);
            s2 += __shfl_xor(s2, 16); s2 += __shfl_xor(s2, 32);
            hval[cc] = s2 / s1;
        }
        if (quad == 0) {
            // fused CE partial: logits bounded (|10h| < ~50) -> no shift
            const int lbl = labels[b];
            float ps = 0.f;
            #pragma unroll
            for (int cc = 0; cc < 8; ++cc) {
                float lg = 10.0f * hval[cc];
                if (lbl == cb + cc) {
                    lg -= 0.1f;               // LMD * MARGIN
                    lab_logit[b] = lg;        // single writer per b
                }
                ps += __expf(lg);
            }
            atomicAdd(&sumexp[b], ps);
        }
    }
}

// ---------------- kernel 3: combine ---------------------------------------
__global__ __launch_bounds__(256) void final_kernel(
    const float* __restrict__ sumexp, const float* __restrict__ lab_logit,
    const float* __restrict__ gram_sum, float* __restrict__ out)
{
    __shared__ float red[4];
    const int t = threadIdx.x, wave = t >> 6, lane = t & 63;
    float val = (logf(sumexp[t]) - lab_logit[t]) * (1.0f / 256.0f);
    #pragma unroll
    for (int off = 32; off; off >>= 1) val += __shfl_xor(val, off);
    if (lane == 0) red[wave] = val;
    __syncthreads();
    if (t == 0)
        out[0] = red[0] + red[1] + red[2] + red[3]
               + gram_sum[0] * (0.2f / 737280.0f);   // C*K*(K-1) = 737280
}

extern "C" void kernel_launch(void* const* d_in, const int* in_sizes, int n_in,
                              void* d_out, int out_size, void* d_ws, size_t ws_size,
                              hipStream_t stream) {
    const float* emb    = (const float*)d_in[0];   // [256][512]
    const int*   labels = (const int*)d_in[1];     // [256]
    const float* fc     = (const float*)d_in[2];   // [81920][512]
    float* out = (float*)d_out;

    char* ws = (char*)d_ws;
    bf16*  At        = (bf16*)ws;                        //    262144 B
    float* sumexp    = (float*)(ws + 262144);            //      1024 B
    float* lab_logit = (float*)(ws + 263168);            //      1024 B
    float* gram_sum  = (float*)(ws + 264192);            //         4 B

    conv_kernel<<<65, 256, 0, stream>>>(emb, At, sumexp, gram_sum);
    gemm_all_kernel<<<NCLASS / 8, 512, 0, stream>>>(fc, At, labels,
                                                    sumexp, lab_logit, gram_sum);
    final_kernel<<<1, 256, 0, stream>>>(sumexp, lab_logit, gram_sum, out);
}